// Round 9
// baseline (603.640 us; speedup 1.0000x reference)
//
#include <hip/hip_runtime.h>

// HardBinaryVote: votes (63, N) int32 in {0,1}; weights (63,) fp32.
// out[j] = (sum_{v[i][j]==1} w[i]) > (sum_{v[i][j]==0} w[i]) ? 1 : 0  (int32)
//
// MEASUREMENT LEDGER (exact, differential rounds):
//   OH (harness reset: ~2GB ws fill + 504MB input restore) = 547.4 us
//   T_B (int4, 256thr)                  = 94.6 us  (5.4 TB/s)
//   T_A (int2, 256thr)                  = 89.5 us
//   T_D (int4, 64thr, nt load)          = 59.6 us  (R7: 607.0)
//   T_E (= D + nt store)                = 56.2 us  (R8: 603.6)
//       Effective 9.1 TB/s > 8.0 HBM peak => ~256 MB of votes served from
//       L3 (restore writes 504 MB right before us). nt probe-not-allocate
//       avoids pollution/invalidation. HBM-resident bytes ~248 MB => memory
//       floor ~38 us; 18 us gap unexplained => try VALU-lean inner before
//       declaring roofline.
// R9 = E with exact fma inner loop: v in {0,1} => f=(float)v, f*wi, (1-f)*wi
// all EXACT, fma(exact-product)+acc == add of {wi,0} in identical order =>
// bit-identical results with 4 VALU/elem instead of 6 (cmp+cndmask+add x2).
//
// CORRECTNESS-CRITICAL (absmax 0.0 R1-R5,R7,R8): replicate numpy pairwise_sum
// for n=63 — 8 accumulators over rows 0..55 (r[k] sums rows k,k+8,..,k+48),
// combine ((r0+r1)+(r2+r3))+((r4+r5)+(r6+r7)), sequential tail rows 56..62 —
// c1/c0 BIT-EXACT vs reference; (c1 > c0) cannot flip on near-ties.
// Do NOT reassociate / fast-math.

#define NM 63

typedef int v4i __attribute__((ext_vector_type(4)));

__global__ __launch_bounds__(64, 4) void hbv_kernel_f(
    const int* __restrict__ votes, const float* __restrict__ wts,
    int* __restrict__ out, int n)
{
    __shared__ float ws[64];
    if (threadIdx.x < NM) ws[threadIdx.x] = wts[threadIdx.x];
    __syncthreads();

    const size_t t  = (size_t)blockIdx.x * blockDim.x + threadIdx.x;
    const size_t j0 = t * 4;
    if (j0 >= (size_t)n) return;

    const size_t row = (size_t)n;

    // numpy pairwise accumulators: r[k] sums rows k, k+8, ..., k+48
    float r1[8][4], r0[8][4];
#pragma unroll
    for (int k = 0; k < 8; ++k)
#pragma unroll
        for (int s = 0; s < 4; ++s) { r1[k][s] = 0.0f; r0[k][s] = 0.0f; }

    // Rows 0..55 in blocks of 8; unroll 1 keeps 8 int4 nt-loads in flight.
#pragma unroll 1
    for (int b = 0; b < 7; ++b) {
        v4i v[8];
#pragma unroll
        for (int k = 0; k < 8; ++k)
            v[k] = __builtin_nontemporal_load(
                (const v4i*)(votes + (size_t)(8 * b + k) * row + j0));
#pragma unroll
        for (int k = 0; k < 8; ++k) {
            const float wi = ws[8 * b + k];
#pragma unroll
            for (int s = 0; s < 4; ++s) {
                const float f = (float)v[k][s];     // exact: {0.0, 1.0}
                r1[k][s] = fmaf(f,        wi, r1[k][s]);  // +wi or +0, exact
                r0[k][s] = fmaf(1.0f - f, wi, r0[k][s]);  // +wi or +0, exact
            }
        }
    }

    // numpy combine order
    float c1[4], c0[4];
#pragma unroll
    for (int s = 0; s < 4; ++s) {
        c1[s] = ((r1[0][s] + r1[1][s]) + (r1[2][s] + r1[3][s]))
              + ((r1[4][s] + r1[5][s]) + (r1[6][s] + r1[7][s]));
        c0[s] = ((r0[0][s] + r0[1][s]) + (r0[2][s] + r0[3][s]))
              + ((r0[4][s] + r0[5][s]) + (r0[6][s] + r0[7][s]));
    }

    // tail rows 56..62, sequential (numpy tail loop)
    {
        v4i v[7];
#pragma unroll
        for (int i = 0; i < 7; ++i)
            v[i] = __builtin_nontemporal_load(
                (const v4i*)(votes + (size_t)(56 + i) * row + j0));
#pragma unroll
        for (int i = 0; i < 7; ++i) {
            const float wi = ws[56 + i];
#pragma unroll
            for (int s = 0; s < 4; ++s) {
                const float f = (float)v[i][s];
                c1[s] = fmaf(f,        wi, c1[s]);
                c0[s] = fmaf(1.0f - f, wi, c0[s]);
            }
        }
    }

    v4i res;
    res[0] = (c1[0] > c0[0]) ? 1 : 0;
    res[1] = (c1[1] > c0[1]) ? 1 : 0;
    res[2] = (c1[2] > c0[2]) ? 1 : 0;
    res[3] = (c1[3] > c0[3]) ? 1 : 0;
    __builtin_nontemporal_store(res, (v4i*)(out + j0));
}

extern "C" void kernel_launch(void* const* d_in, const int* in_sizes, int n_in,
                              void* d_out, int out_size, void* d_ws, size_t ws_size,
                              hipStream_t stream)
{
    const int*   votes = (const int*)d_in[0];
    const float* wts   = (const float*)d_in[1];
    int*         out   = (int*)d_out;
    const int n = out_size;                 // N_SAMPLES = 2,000,000

    const int threads  = 64;                // 1 wave/block, fine granularity
    const int nthreads = (n + 3) / 4;       // one thread per 4 samples
    const int blocks   = (nthreads + threads - 1) / threads;   // 7813

    hipLaunchKernelGGL(hbv_kernel_f, dim3(blocks), dim3(threads), 0, stream,
                       votes, wts, out, n);
}